// Round 3
// baseline (181.174 us; speedup 1.0000x reference)
//
#include <hip/hip_runtime.h>
#include <math.h>

#define H 256
#define OUTD 218
#define OUTP 224
#define BMT 64                  // rows per tile
#define NBATCH 64
#define NPTS 4096
#define NTOT (NBATCH * NPTS)
#define NBLK 256                // persistent blocks, 1 per CU
#define TPB 16                  // tiles per block = NTOT/BMT/NBLK
#define THREADS 512
#define PCOLS 218               // 217 numerator cols + denom

typedef __attribute__((ext_vector_type(8))) short bf16x8;
typedef __attribute__((ext_vector_type(4))) float f32x4;

// RNE f32->bf16 bit-trick (compiler-schedulable; NOT inline-asm cvt_pk — m240)
static __device__ __forceinline__ unsigned short f2bf(float f) {
  union { float f; unsigned int u; } v;
  v.f = f;
  unsigned int u = v.u;
  return (unsigned short)((u + 0x7FFFu + ((u >> 16) & 1u)) >> 16);
}

static __device__ __forceinline__ bf16x8 pack8(float4 a, float4 b) {
  bf16x8 r;
  r[0] = (short)f2bf(a.x); r[1] = (short)f2bf(a.y);
  r[2] = (short)f2bf(a.z); r[3] = (short)f2bf(a.w);
  r[4] = (short)f2bf(b.x); r[5] = (short)f2bf(b.y);
  r[6] = (short)f2bf(b.z); r[7] = (short)f2bf(b.w);
  return r;
}

// W1T[j][k] = bf16(W1[k][j]) (256x256); W2T[j][k] = bf16(W2[k][j]) (224x256, padded)
__global__ __launch_bounds__(256) void prep_kernel(
    const float* __restrict__ W1, const float* __restrict__ W2,
    unsigned short* __restrict__ w1t, unsigned short* __restrict__ w2t) {
  int j = blockIdx.x;
  int k = threadIdx.x;
  if (j < H) {
    w1t[j * H + k] = f2bf(W1[k * H + j]);
  } else {
    int jj = j - H;
    w2t[jj * H + k] = (jj < OUTD) ? f2bf(W2[k * OUTD + jj]) : (unsigned short)0;
  }
}

// raw barrier: drain own LDS ops, sync — global loads stay in flight
#define BAR()                                            \
  {                                                      \
    asm volatile("s_waitcnt lgkmcnt(0)" ::: "memory");   \
    __builtin_amdgcn_s_barrier();                        \
  }

// Producer-consumer crew kernel:
//  crew1 = waves 0-3: GEMM1(t) (4 coltiles each) + leaky-h -> hbuf
//  crew2 = waves 4-7: GEMM2(t-1) (4/4/3/3 coltiles) + exp + psum
//  One s_barrier per window; exp->psum ordered by an LDS flag handshake.
__global__ __launch_bounds__(THREADS, 2) void fused_kernel(
    const float* __restrict__ pe, const float* __restrict__ b1g,
    const float* __restrict__ b2g, const unsigned short* __restrict__ w1t,
    const unsigned short* __restrict__ w2t, float* __restrict__ part) {
  __shared__ __align__(16) unsigned short afrag[2 * BMT * H];  // 64 KB dbuf, fragment-linear bf16
  __shared__ __align__(16) unsigned short hbuf2[2 * BMT * H];  // 64 KB dbuf, fragment-linear bf16
  __shared__ __align__(16) float e_lds[BMT];
  __shared__ int flagv;

  const int tid = threadIdx.x;
  const int blk = blockIdx.x;
  const int w = tid >> 6;
  const int l = tid & 63;
  const int l15 = l & 15;
  const int hi = l >> 4;
  const bool isC1 = (w < 4);
  const size_t row0 = (size_t)blk * (BMT * TPB);   // 1024 rows/block

  // ---- role geometry ----
  int ctbase, nct;
  if (isC1) { ctbase = w * 4; nct = 4; }
  else {
    const int w2 = w - 4;
    if (w2 < 2) { ctbase = w2 * 4; nct = 4; }       // cts 0-3, 4-7
    else        { ctbase = 8 + (w2 - 2) * 3; nct = 3; }  // cts 8-10, 11-13
  }

  // ---- persistent weight fragments — UNION'd storage (crew1:W1 / crew2:W2)
  // (separate arrays would be cross-branch live -> 256 regs of weights -> spill)
  const unsigned short* wt = isC1 ? w1t : w2t;
  const float* bg = isC1 ? b1g : b2g;
  bf16x8 br[4][8];
  float bcol[4];
  int jcol[4];
  #pragma unroll
  for (int cc = 0; cc < 4; ++cc) {
    const int col = (ctbase + cc) * 16 + l15;
    jcol[cc] = col;
    bcol[cc] = 0.f;
    if (cc < nct) {
      bcol[cc] = (isC1 || col < OUTD) ? bg[col] : 0.f;
      #pragma unroll
      for (int s = 0; s < 8; ++s)
        br[cc][s] = *reinterpret_cast<const bf16x8*>(wt + col * H + s * 32 + hi * 8);
    }
  }

  if (tid == 0) flagv = 0;

  // ---- reg-staged prefetch bank: 16 VGPR, cycled twice per window ----
  // tile = 2048 chunks of 32B; chunk idx: row = idx>>5, k8 = idx&31.
  // crew1 owns rows 0-31 (idx 0..1023), crew2 rows 32-63 (idx 1024..2047).
  float4 ld[2][2];
  const int bidx = (isC1 ? 0 : 1024) + (tid & 255);
#define ISSUE(T, hh)                                                         \
  {                                                                          \
    const float* g = pe + (row0 + (size_t)(T) * BMT) * H;                    \
    _Pragma("unroll") for (int jj = 0; jj < 2; ++jj) {                       \
      const int idx = bidx + (hh) * 512 + jj * 256;                          \
      const float* a = g + (idx >> 5) * H + (idx & 31) * 8;                  \
      ld[jj][0] = *(const float4*)a;                                         \
      ld[jj][1] = *(const float4*)(a + 4);                                   \
    }                                                                        \
  }
  // fragment-linear convert (identical mapping to r2's verified layout)
#define CVT(buf, hh)                                                         \
  {                                                                          \
    unsigned short* dst = afrag + (buf) * (BMT * H);                         \
    _Pragma("unroll") for (int jj = 0; jj < 2; ++jj) {                       \
      const int idx = bidx + (hh) * 512 + jj * 256;                          \
      const int row = idx >> 5, k8 = idx & 31;                               \
      const int ff = row >> 4, ss = k8 >> 2, h2 = k8 & 3, ll = row & 15;     \
      const int p = (ll * 4 + h2 + ss) & 63;                                 \
      *(bf16x8*)&dst[(ff * 8 + ss) * 512 + p * 8] = pack8(ld[jj][0], ld[jj][1]); \
    }                                                                        \
  }

  // ---- prologue: stage tile 0 (two bank cycles), put half0 of tile 1 in flight ----
  ISSUE(0, 0);
  __builtin_amdgcn_sched_barrier(0);
  CVT(0, 0);
  __builtin_amdgcn_sched_barrier(0);
  ISSUE(0, 1);
  __builtin_amdgcn_sched_barrier(0);
  CVT(0, 1);
  __builtin_amdgcn_sched_barrier(0);
  ISSUE(1, 0);
  BAR();     // afrag[0] complete; flagv visible

  float psum[4] = {0.f, 0.f, 0.f, 0.f};
  float dsum = 0.f;

  // windows: W(t) runs crew1 on tile t, crew2 on tile t-1; t = 0..TPB inclusive
  for (int t = 0; t <= TPB; ++t) {
    const bool haveN = (t + 1 < TPB);

    if (isC1) {
      if (t < TPB) {
        const unsigned short* A = afrag + (t & 1) * (BMT * H);
        unsigned short* hdst = hbuf2 + (t & 1) * (BMT * H);

        if (haveN) {
          __builtin_amdgcn_sched_barrier(0);
          CVT((t + 1) & 1, 0);               // bank holds half0(t+1) from last window
          __builtin_amdgcn_sched_barrier(0);
          ISSUE(t + 1, 1);                   // refill: half1(t+1)
        }

        // GEMM1: 4 f-frags x 4 coltiles, k=256
        f32x4 acc[4][4];
        #pragma unroll
        for (int f = 0; f < 4; ++f)
          #pragma unroll
          for (int cc = 0; cc < 4; ++cc) acc[f][cc] = (f32x4)0.f;
        __builtin_amdgcn_s_setprio(1);
        #pragma unroll
        for (int s = 0; s < 8; ++s) {
          const int p = (l15 * 4 + hi + s) & 63;
          bf16x8 af[4];
          #pragma unroll
          for (int f = 0; f < 4; ++f)
            af[f] = *(const bf16x8*)&A[(f * 8 + s) * 512 + p * 8];
          #pragma unroll
          for (int f = 0; f < 4; ++f)
            #pragma unroll
            for (int cc = 0; cc < 4; ++cc)
              acc[f][cc] = __builtin_amdgcn_mfma_f32_16x16x32_bf16(af[f], br[cc][s], acc[f][cc], 0, 0, 0);
        }
        __builtin_amdgcn_s_setprio(0);

        // h = leaky(acc + b1) -> hbuf[t&1], fragment-linear
        #pragma unroll
        for (int cc = 0; cc < 4; ++cc) {
          const int col = (ctbase + cc) * 16 + l15;
          const int s2 = col >> 5;
          const int hb_ = (col >> 3) & 3;
          const int j2 = col & 7;
          #pragma unroll
          for (int f = 0; f < 4; ++f)
            #pragma unroll
            for (int r = 0; r < 4; ++r) {
              const int rl = hi * 4 + r;
              float hv = acc[f][cc][r] + bcol[cc];
              hv = fmaxf(hv, 0.02f * hv);
              const int p2 = (rl * 4 + hb_ + s2) & 63;
              hdst[(f * 8 + s2) * 512 + p2 * 8 + j2] = f2bf(hv);
            }
        }

        if (haveN) {
          __builtin_amdgcn_sched_barrier(0);
          CVT((t + 1) & 1, 1);
          __builtin_amdgcn_sched_barrier(0);
          if (t + 2 < TPB) ISSUE(t + 2, 0);
        }
      }
    } else {
      if (haveN) {
        __builtin_amdgcn_sched_barrier(0);
        CVT((t + 1) & 1, 0);
        __builtin_amdgcn_sched_barrier(0);
        ISSUE(t + 1, 1);
      }

      if (t >= 1) {
        const unsigned short* Ah = hbuf2 + ((t - 1) & 1) * (BMT * H);

        // GEMM2: ae(t-1) = h @ W2
        f32x4 acc[4][4];
        #pragma unroll
        for (int f = 0; f < 4; ++f)
          #pragma unroll
          for (int cc = 0; cc < 4; ++cc) acc[f][cc] = (f32x4)0.f;
        __builtin_amdgcn_s_setprio(1);
        #pragma unroll
        for (int s = 0; s < 8; ++s) {
          const int p = (l15 * 4 + hi + s) & 63;
          bf16x8 af[4];
          #pragma unroll
          for (int f = 0; f < 4; ++f)
            af[f] = *(const bf16x8*)&Ah[(f * 8 + s) * 512 + p * 8];
          #pragma unroll
          for (int f = 0; f < 4; ++f)
            #pragma unroll
            for (int cc = 0; cc < 3; ++cc)
              acc[f][cc] = __builtin_amdgcn_mfma_f32_16x16x32_bf16(af[f], br[cc][s], acc[f][cc], 0, 0, 0);
          if (nct == 4) {
            #pragma unroll
            for (int f = 0; f < 4; ++f)
              acc[f][3] = __builtin_amdgcn_mfma_f32_16x16x32_bf16(af[f], br[3][s], acc[f][3], 0, 0, 0);
          }
        }
        __builtin_amdgcn_s_setprio(0);

        // exp: wave 4 owns coltile 0 -> col 0 logits on l15==0 lanes
        if (w == 4) {
          if (l15 == 0) {
            #pragma unroll
            for (int f = 0; f < 4; ++f) {
              f32x4 ev;
              #pragma unroll
              for (int r = 0; r < 4; ++r) ev[r] = __expf(acc[f][0][r] + bcol[0]);
              *(f32x4*)&e_lds[f * 16 + hi * 4] = ev;
            }
          }
          asm volatile("s_waitcnt lgkmcnt(0)" ::: "memory");  // e in LDS before flag
          if (l == 0) *(volatile int*)&flagv = t;
        }
        // handshake: crew2 waits for e (crew1 never waits here)
        {
          volatile const int* fp = (volatile const int*)&flagv;
          while (*fp != t) { }
          asm volatile("" ::: "memory");     // no e_lds reads hoisted above spin
        }

        // psum accumulate
        #pragma unroll
        for (int f = 0; f < 4; ++f) {
          const f32x4 ev = *(const f32x4*)&e_lds[f * 16 + hi * 4];
          #pragma unroll
          for (int r = 0; r < 4; ++r) {
            psum[0] += ev[r] * (acc[f][0][r] + bcol[0]);
            psum[1] += ev[r] * (acc[f][1][r] + bcol[1]);
            psum[2] += ev[r] * (acc[f][2][r] + bcol[2]);
            if (nct == 4) psum[3] += ev[r] * (acc[f][3][r] + bcol[3]);
          }
        }
        if (w == 5) dsum += e_lds[l];
      }

      if (haveN) {
        __builtin_amdgcn_sched_barrier(0);
        CVT((t + 1) & 1, 1);
        __builtin_amdgcn_sched_barrier(0);
        if (t + 2 < TPB) ISSUE(t + 2, 0);
      }
    }

    BAR();   // h(t) -> GEMM2(t) [next window]; CVT(t+1) -> GEMM1(t+1)
  }

  // ---- store per-block partials (no atomics) ----
  if (!isC1) {
    #pragma unroll
    for (int cc = 0; cc < 4; ++cc) {
      psum[cc] += __shfl_xor(psum[cc], 16);
      psum[cc] += __shfl_xor(psum[cc], 32);
    }
    if (hi == 0) {
      for (int cc = 0; cc < nct; ++cc) {
        int j = jcol[cc];
        if (j >= 1 && j < OUTD) part[blk * PCOLS + (j - 1)] = psum[cc];
      }
    }
  }
  if (w == 5) {
    #pragma unroll
    for (int m = 1; m < 64; m <<= 1) dsum += __shfl_xor(dsum, m);
    if (l == 0) part[blk * PCOLS + 217] = dsum;
  }
#undef ISSUE
#undef CVT
}

__global__ __launch_bounds__(256) void finalize_kernel(
    const float* __restrict__ part, float* __restrict__ out) {
  int b = blockIdx.x;
  int t = threadIdx.x;
  if (t < 217) {
    float s = 0.f, d = 0.f;
    #pragma unroll
    for (int i = 0; i < NBLK / NBATCH; ++i) {   // 4 blocks per batch
      const float* p = part + (size_t)(b * (NBLK / NBATCH) + i) * PCOLS;
      s += p[t];
      d += p[217];
    }
    float v = s / d;
    if (t < 216) out[b * 216 + t] = v;        // xr: (64, 72, 3) flat
    else out[NBATCH * 216 + b] = v;           // xo: (64,)
  }
}

extern "C" void kernel_launch(void* const* d_in, const int* in_sizes, int n_in,
                              void* d_out, int out_size, void* d_ws, size_t ws_size,
                              hipStream_t stream) {
  (void)in_sizes; (void)n_in; (void)out_size; (void)ws_size;
  const float* pe = (const float*)d_in[0];
  const float* W1 = (const float*)d_in[1];
  const float* b1 = (const float*)d_in[2];
  const float* W2 = (const float*)d_in[3];
  const float* b2 = (const float*)d_in[4];

  unsigned short* w1t = (unsigned short*)d_ws;          // 131072 B
  unsigned short* w2t = w1t + H * H;                    // 114688 B
  float* part = (float*)((char*)d_ws + (H * H + OUTP * H) * 2);  // 256*218*4 B

  prep_kernel<<<H + OUTP, 256, 0, stream>>>(W1, W2, w1t, w2t);
  fused_kernel<<<NBLK, THREADS, 0, stream>>>(pe, b1, b2, w1t, w2t, part);
  finalize_kernel<<<NBATCH, 256, 0, stream>>>(part, (float*)d_out);
}

// Round 4
// 166.626 us; speedup vs baseline: 1.0873x; 1.0873x over previous
//
#include <hip/hip_runtime.h>
#include <math.h>

#define H 256
#define OUTD 218
#define OUTP 224
#define BMT 64                  // rows per tile
#define NBATCH 64
#define NPTS 4096
#define NTOT (NBATCH * NPTS)
#define NBLK 256                // persistent blocks, 1 per CU
#define TPB 16                  // tiles per block = NTOT/BMT/NBLK
#define THREADS 512
#define PCOLS 218               // 217 numerator cols + denom

typedef __attribute__((ext_vector_type(8))) short bf16x8;
typedef __attribute__((ext_vector_type(4))) float f32x4;

// RNE f32->bf16 bit-trick (compiler-schedulable; NOT inline-asm cvt_pk — m240)
static __device__ __forceinline__ unsigned short f2bf(float f) {
  union { float f; unsigned int u; } v;
  v.f = f;
  unsigned int u = v.u;
  return (unsigned short)((u + 0x7FFFu + ((u >> 16) & 1u)) >> 16);
}

static __device__ __forceinline__ bf16x8 pack8(float4 a, float4 b) {
  bf16x8 r;
  r[0] = (short)f2bf(a.x); r[1] = (short)f2bf(a.y);
  r[2] = (short)f2bf(a.z); r[3] = (short)f2bf(a.w);
  r[4] = (short)f2bf(b.x); r[5] = (short)f2bf(b.y);
  r[6] = (short)f2bf(b.z); r[7] = (short)f2bf(b.w);
  return r;
}

// W1T[j][k] = bf16(W1[k][j]) (256x256); W2T[j][k] = bf16(W2[k][j]) (224x256, padded)
__global__ __launch_bounds__(256) void prep_kernel(
    const float* __restrict__ W1, const float* __restrict__ W2,
    unsigned short* __restrict__ w1t, unsigned short* __restrict__ w2t) {
  int j = blockIdx.x;
  int k = threadIdx.x;
  if (j < H) {
    w1t[j * H + k] = f2bf(W1[k * H + j]);
  } else {
    int jj = j - H;
    w2t[jj * H + k] = (jj < OUTD) ? f2bf(W2[k * OUTD + jj]) : (unsigned short)0;
  }
}

// raw barrier: drain own LDS ops, sync — global loads stay in flight
#define BAR()                                            \
  {                                                      \
    asm volatile("s_waitcnt lgkmcnt(0)" ::: "memory");   \
    __builtin_amdgcn_s_barrier();                        \
  }

// Producer-consumer crew kernel, 2 barriers/window, no spin-flag:
//  crew1 = waves 0-3: GEMM1(t) (W1 coltiles 4w..4w+3) + leaky-h -> hbuf
//  crew2 = waves 4-7: GEMM2(t-1): w4:{3-6} w5:{7-10} w6:{0-2}+exp w7:{11-13}+dsum
//  Window: [GEMM1(t) | GEMM2(t-1)+exp] BAR [h-write | psum] + CVT/ISSUE BAR
// amdgpu_waves_per_eu(2,2): pin allocator to 2 waves/EU (1 block/CU @ 128.5KB
// LDS) -> full 256-VGPR budget. r3's failure: allocator chose 128 VGPR (4/EU
// target) and spilled the 128-VGPR weight array -> 2.6x regression.
__global__ __launch_bounds__(THREADS) __attribute__((amdgpu_waves_per_eu(2, 2)))
void fused_kernel(
    const float* __restrict__ pe, const float* __restrict__ b1g,
    const float* __restrict__ b2g, const unsigned short* __restrict__ w1t,
    const unsigned short* __restrict__ w2t, float* __restrict__ part) {
  __shared__ __align__(16) unsigned short afrag[2 * BMT * H];  // 64 KB dbuf, fragment-linear bf16
  __shared__ __align__(16) unsigned short hbuf2[2 * BMT * H];  // 64 KB dbuf, fragment-linear bf16
  __shared__ __align__(16) float e_lds[BMT];

  const int tid = threadIdx.x;
  const int blk = blockIdx.x;
  const int w = tid >> 6;
  const int l = tid & 63;
  const int l15 = l & 15;
  const int hi = l >> 4;
  const bool isC1 = (w < 4);
  const size_t row0 = (size_t)blk * (BMT * TPB);   // 1024 rows/block

  // ---- role geometry (exp on a 3-coltile wave so it hides in MFMA slack) ----
  int ctbase, nct;
  if (isC1)        { ctbase = w * 4; nct = 4; }
  else if (w == 4) { ctbase = 3;     nct = 4; }
  else if (w == 5) { ctbase = 7;     nct = 4; }
  else if (w == 6) { ctbase = 0;     nct = 3; }   // owns coltile 0 -> exp
  else             { ctbase = 11;    nct = 3; }   // dsum

  // ---- persistent weight fragments (crew1: W1, crew2: W2) — 128 VGPRs ----
  const unsigned short* wt = isC1 ? w1t : w2t;
  const float* bg = isC1 ? b1g : b2g;
  bf16x8 br[4][8];
  float bcol[4];
  #pragma unroll
  for (int cc = 0; cc < 4; ++cc) {
    const int col = (ctbase + cc) * 16 + l15;
    bcol[cc] = 0.f;
    if (cc < nct) {
      bcol[cc] = (isC1 || col < OUTD) ? bg[col] : 0.f;
      #pragma unroll
      for (int s = 0; s < 8; ++s)
        br[cc][s] = *reinterpret_cast<const bf16x8*>(wt + col * H + s * 32 + hi * 8);
    }
  }

  // ---- reg-staged prefetch bank: 16 VGPR, cycled twice per window ----
  // chunk idx: row = idx>>5, k8 = idx&31 (32B each). crew1 owns idx 0..1023
  // (rows 0-31), crew2 idx 1024..2047 (rows 32-63).
  float4 ld[2][2];
  const int bidx = (isC1 ? 0 : 1024) + (tid & 255);
#define ISSUE(T, hh)                                                         \
  {                                                                          \
    const float* g = pe + (row0 + (size_t)(T) * BMT) * H;                    \
    _Pragma("unroll") for (int jj = 0; jj < 2; ++jj) {                       \
      const int idx = bidx + (hh) * 512 + jj * 256;                          \
      const float* a = g + (idx >> 5) * H + (idx & 31) * 8;                  \
      ld[jj][0] = *(const float4*)a;                                         \
      ld[jj][1] = *(const float4*)(a + 4);                                   \
    }                                                                        \
  }
  // fragment-linear convert (identical mapping to r2's verified layout)
#define CVT(buf, hh)                                                         \
  {                                                                          \
    unsigned short* dst = afrag + (buf) * (BMT * H);                         \
    _Pragma("unroll") for (int jj = 0; jj < 2; ++jj) {                       \
      const int idx = bidx + (hh) * 512 + jj * 256;                          \
      const int row = idx >> 5, k8 = idx & 31;                               \
      const int ff = row >> 4, ss = k8 >> 2, h2 = k8 & 3, ll = row & 15;     \
      const int p = (ll * 4 + h2 + ss) & 63;                                 \
      *(bf16x8*)&dst[(ff * 8 + ss) * 512 + p * 8] = pack8(ld[jj][0], ld[jj][1]); \
    }                                                                        \
  }

  // ---- prologue: stage tile 0, put half0 of tile 1 in flight ----
  ISSUE(0, 0);
  __builtin_amdgcn_sched_barrier(0);
  CVT(0, 0);
  __builtin_amdgcn_sched_barrier(0);
  ISSUE(0, 1);
  __builtin_amdgcn_sched_barrier(0);
  CVT(0, 1);
  __builtin_amdgcn_sched_barrier(0);
  ISSUE(1, 0);
  BAR();     // afrag[0] complete

  float psum[4] = {0.f, 0.f, 0.f, 0.f};
  float dsum = 0.f;
  f32x4 acc[4][4];           // written phase1, consumed phase2 (per-crew use)

  // windows: W(t) = crew1 on tile t, crew2 on tile t-1; t = 0..TPB inclusive
  for (int t = 0; t <= TPB; ++t) {
    const bool haveN = (t + 1 < TPB);

    // ================= phase 1: GEMMs =================
    if (isC1) {
      if (t < TPB) {
        const unsigned short* A = afrag + (t & 1) * (BMT * H);
        #pragma unroll
        for (int f = 0; f < 4; ++f)
          #pragma unroll
          for (int cc = 0; cc < 4; ++cc) acc[f][cc] = (f32x4)0.f;
        __builtin_amdgcn_s_setprio(1);
        #pragma unroll
        for (int s = 0; s < 8; ++s) {
          const int p = (l15 * 4 + hi + s) & 63;
          bf16x8 af[4];
          #pragma unroll
          for (int f = 0; f < 4; ++f)
            af[f] = *(const bf16x8*)&A[(f * 8 + s) * 512 + p * 8];
          #pragma unroll
          for (int f = 0; f < 4; ++f)
            #pragma unroll
            for (int cc = 0; cc < 4; ++cc)
              acc[f][cc] = __builtin_amdgcn_mfma_f32_16x16x32_bf16(af[f], br[cc][s], acc[f][cc], 0, 0, 0);
        }
        __builtin_amdgcn_s_setprio(0);
      }
    } else {
      if (t >= 1) {
        const unsigned short* Ah = hbuf2 + ((t - 1) & 1) * (BMT * H);
        #pragma unroll
        for (int f = 0; f < 4; ++f)
          #pragma unroll
          for (int cc = 0; cc < 4; ++cc) acc[f][cc] = (f32x4)0.f;
        __builtin_amdgcn_s_setprio(1);
        #pragma unroll
        for (int s = 0; s < 8; ++s) {
          const int p = (l15 * 4 + hi + s) & 63;
          bf16x8 af[4];
          #pragma unroll
          for (int f = 0; f < 4; ++f)
            af[f] = *(const bf16x8*)&Ah[(f * 8 + s) * 512 + p * 8];
          #pragma unroll
          for (int f = 0; f < 4; ++f)
            #pragma unroll
            for (int cc = 0; cc < 3; ++cc)
              acc[f][cc] = __builtin_amdgcn_mfma_f32_16x16x32_bf16(af[f], br[cc][s], acc[f][cc], 0, 0, 0);
          if (nct == 4) {
            #pragma unroll
            for (int f = 0; f < 4; ++f)
              acc[f][3] = __builtin_amdgcn_mfma_f32_16x16x32_bf16(af[f], br[3][s], acc[f][3], 0, 0, 0);
          }
        }
        __builtin_amdgcn_s_setprio(0);

        // exp: wave 6 owns coltile 0 -> col-0 logits on l15==0 lanes
        if (w == 6 && l15 == 0) {
          #pragma unroll
          for (int f = 0; f < 4; ++f) {
            f32x4 ev;
            #pragma unroll
            for (int r = 0; r < 4; ++r) ev[r] = __expf(acc[f][0][r] + bcol[0]);
            *(f32x4*)&e_lds[f * 16 + hi * 4] = ev;
          }
        }
      }
    }
    if (haveN) {
      __builtin_amdgcn_sched_barrier(0);
      CVT((t + 1) & 1, 0);               // bank: half0(t+1), issued last window
      __builtin_amdgcn_sched_barrier(0);
      ISSUE(t + 1, 1);                   // refill: half1(t+1)
    }
    BAR();   // BAR_A: e_lds visible (lgkmcnt drains exp + CVT writes)

    // ================= phase 2: h-write | psum =================
    if (isC1) {
      if (t < TPB) {
        unsigned short* hdst = hbuf2 + (t & 1) * (BMT * H);
        #pragma unroll
        for (int cc = 0; cc < 4; ++cc) {
          const int col = (ctbase + cc) * 16 + l15;
          const int s2 = col >> 5;
          const int hb_ = (col >> 3) & 3;
          const int j2 = col & 7;
          #pragma unroll
          for (int f = 0; f < 4; ++f)
            #pragma unroll
            for (int r = 0; r < 4; ++r) {
              const int rl = hi * 4 + r;
              float hv = acc[f][cc][r] + bcol[cc];
              hv = fmaxf(hv, 0.02f * hv);
              const int p2 = (rl * 4 + hb_ + s2) & 63;
              hdst[(f * 8 + s2) * 512 + p2 * 8 + j2] = f2bf(hv);
            }
        }
      }
    } else {
      if (t >= 1) {
        #pragma unroll
        for (int f = 0; f < 4; ++f) {
          const f32x4 ev = *(const f32x4*)&e_lds[f * 16 + hi * 4];
          #pragma unroll
          for (int r = 0; r < 4; ++r) {
            psum[0] += ev[r] * (acc[f][0][r] + bcol[0]);
            psum[1] += ev[r] * (acc[f][1][r] + bcol[1]);
            psum[2] += ev[r] * (acc[f][2][r] + bcol[2]);
            if (nct == 4) psum[3] += ev[r] * (acc[f][3][r] + bcol[3]);
          }
        }
        if (w == 7) dsum += e_lds[l];
      }
    }
    if (haveN) {
      __builtin_amdgcn_sched_barrier(0);
      CVT((t + 1) & 1, 1);               // bank: half1(t+1), flew across GEMMs
      __builtin_amdgcn_sched_barrier(0);
      if (t + 2 < TPB) ISSUE(t + 2, 0);  // flight spans BAR_B + next GEMMs
    }
    BAR();   // BAR_B: h(t)->GEMM2(t); CVT(t+1)->GEMM1(t+1); e_lds reads done
  }

  // ---- store per-block partials (no atomics) ----
  if (!isC1) {
    #pragma unroll
    for (int cc = 0; cc < 4; ++cc) {
      psum[cc] += __shfl_xor(psum[cc], 16);
      psum[cc] += __shfl_xor(psum[cc], 32);
    }
    if (hi == 0) {
      for (int cc = 0; cc < nct; ++cc) {
        const int j = (ctbase + cc) * 16 + l15;
        if (j >= 1 && j < OUTD) part[blk * PCOLS + (j - 1)] = psum[cc];
      }
    }
    if (w == 7) {
      #pragma unroll
      for (int m = 1; m < 64; m <<= 1) dsum += __shfl_xor(dsum, m);
      if (l == 0) part[blk * PCOLS + 217] = dsum;
    }
  }
#undef ISSUE
#undef CVT
}

__global__ __launch_bounds__(256) void finalize_kernel(
    const float* __restrict__ part, float* __restrict__ out) {
  int b = blockIdx.x;
  int t = threadIdx.x;
  if (t < 217) {
    float s = 0.f, d = 0.f;
    #pragma unroll
    for (int i = 0; i < NBLK / NBATCH; ++i) {   // 4 blocks per batch
      const float* p = part + (size_t)(b * (NBLK / NBATCH) + i) * PCOLS;
      s += p[t];
      d += p[217];
    }
    float v = s / d;
    if (t < 216) out[b * 216 + t] = v;        // xr: (64, 72, 3) flat
    else out[NBATCH * 216 + b] = v;           // xo: (64,)
  }
}

extern "C" void kernel_launch(void* const* d_in, const int* in_sizes, int n_in,
                              void* d_out, int out_size, void* d_ws, size_t ws_size,
                              hipStream_t stream) {
  (void)in_sizes; (void)n_in; (void)out_size; (void)ws_size;
  const float* pe = (const float*)d_in[0];
  const float* W1 = (const float*)d_in[1];
  const float* b1 = (const float*)d_in[2];
  const float* W2 = (const float*)d_in[3];
  const float* b2 = (const float*)d_in[4];

  unsigned short* w1t = (unsigned short*)d_ws;          // 131072 B
  unsigned short* w2t = w1t + H * H;                    // 114688 B
  float* part = (float*)((char*)d_ws + (H * H + OUTP * H) * 2);  // 256*218*4 B

  prep_kernel<<<H + OUTP, 256, 0, stream>>>(W1, W2, w1t, w2t);
  fused_kernel<<<NBLK, THREADS, 0, stream>>>(pe, b1, b2, w1t, w2t, part);
  finalize_kernel<<<NBATCH, 256, 0, stream>>>(part, (float*)d_out);
}

// Round 5
// 98.265 us; speedup vs baseline: 1.8437x; 1.6957x over previous
//
#include <hip/hip_runtime.h>
#include <math.h>

#define H 256
#define OUTD 218
#define OUTP 224
#define BMT 64                  // rows per tile
#define NBATCH 64
#define NPTS 4096
#define NTOT (NBATCH * NPTS)
#define NBLK 256                // persistent blocks, 1 per CU
#define TPB 16                  // tiles per block = NTOT/BMT/NBLK
#define THREADS 512
#define PCOLS 218               // 217 numerator cols + denom

typedef __attribute__((ext_vector_type(8))) short bf16x8;
typedef __attribute__((ext_vector_type(4))) float f32x4;

// RNE f32->bf16 bit-trick (compiler-schedulable; NOT inline-asm cvt_pk — m240)
static __device__ __forceinline__ unsigned short f2bf(float f) {
  union { float f; unsigned int u; } v;
  v.f = f;
  unsigned int u = v.u;
  return (unsigned short)((u + 0x7FFFu + ((u >> 16) & 1u)) >> 16);
}

static __device__ __forceinline__ bf16x8 pack8(float4 a, float4 b) {
  bf16x8 r;
  r[0] = (short)f2bf(a.x); r[1] = (short)f2bf(a.y);
  r[2] = (short)f2bf(a.z); r[3] = (short)f2bf(a.w);
  r[4] = (short)f2bf(b.x); r[5] = (short)f2bf(b.y);
  r[6] = (short)f2bf(b.z); r[7] = (short)f2bf(b.w);
  return r;
}

// W1T[j][k] = bf16(W1[k][j]) (256x256); W2T[j][k] = bf16(W2[k][j]) (224x256, padded)
__global__ __launch_bounds__(256) void prep_kernel(
    const float* __restrict__ W1, const float* __restrict__ W2,
    unsigned short* __restrict__ w1t, unsigned short* __restrict__ w2t) {
  int j = blockIdx.x;
  int k = threadIdx.x;
  if (j < H) {
    w1t[j * H + k] = f2bf(W1[k * H + j]);
  } else {
    int jj = j - H;
    w2t[jj * H + k] = (jj < OUTD) ? f2bf(W2[k * OUTD + jj]) : (unsigned short)0;
  }
}

// raw barrier: drain own LDS ops, sync — global loads stay in flight
#define BAR()                                            \
  {                                                      \
    asm volatile("s_waitcnt lgkmcnt(0)" ::: "memory");   \
    __builtin_amdgcn_s_barrier();                        \
  }

__global__ __launch_bounds__(THREADS, 2) void fused_kernel(
    const float* __restrict__ pe, const float* __restrict__ b1g,
    const float* __restrict__ b2g, const unsigned short* __restrict__ w1t,
    const unsigned short* __restrict__ w2t, float* __restrict__ part) {
  // afrag: CVT-writer-uniform layout (r2-verified). hbuf: NEW writer-contiguous
  // layout — h-writes were the 7.34M-cycle bank-conflict source (r3/r4 PMC):
  // old p2=(rl*4+hb+s2)&63 folds hi 2-way onto 8 banks (~4-way conflict on all
  // 32 stores/lane/tile). New p = (hb&1)|(rl>>2)<<1|(hb>>1)<<3|(rl&3)<<4:
  // writer inst -> 128 contiguous bytes (one bank-row, 0 conflicts); reader
  // lanes -> 64 distinct 16B rows (conflict-free ds_read_b128).
  __shared__ __align__(16) unsigned short afrag[2 * BMT * H];  // 2 x 32 KB, fragment-linear bf16
  __shared__ __align__(16) unsigned short hbuf[BMT * H];       // 32 KB, writer-contiguous bf16
  __shared__ __align__(16) float e_lds[BMT];

  const int tid = threadIdx.x;
  const int blk = blockIdx.x;
  const int w = tid >> 6;
  const int l = tid & 63;
  const int l15 = l & 15;
  const int hi = l >> 4;
  const size_t row0 = (size_t)blk * (BMT * TPB);   // 1024 rows/block, batch = blk>>2

  // ---- persistent B fragments (loaded once; steady-state VMEM = pe prefetch only) ----
  const int nct2 = (w < 6) ? 2 : 1;
  bf16x8 b1r[2][8], b2r[2][8];
  int jcol[2];
  float bc1[2], bj2[2];
  #pragma unroll
  for (int cc = 0; cc < 2; ++cc) {
    const int col1 = (2 * w + cc) * 16 + l15;
    const int ct2 = (w < 6) ? (2 * w + cc) : (6 + w);  // w6->12, w7->13
    const int col2 = ct2 * 16 + l15;
    jcol[cc] = col2;
    bc1[cc] = b1g[col1];
    bj2[cc] = (col2 < OUTD) ? b2g[col2] : 0.f;
    #pragma unroll
    for (int s = 0; s < 8; ++s) {
      const int k0 = s * 32 + hi * 8;
      b1r[cc][s] = *reinterpret_cast<const bf16x8*>(w1t + col1 * H + k0);
      b2r[cc][s] = *reinterpret_cast<const bf16x8*>(w2t + col2 * H + k0);
    }
  }
  const float b2c0 = b2g[0];

  // ---- reg-staged prefetch: tile T's pe rows -> ld[4][2] (32 VGPRs in flight) ----
  float4 ld[4][2];
#define ISSUE(T)                                                             \
  {                                                                          \
    const float* g = pe + (row0 + (size_t)(T) * BMT) * H;                    \
    _Pragma("unroll") for (int j2 = 0; j2 < 4; ++j2) {                       \
      const int idx = tid + j2 * THREADS;                                    \
      const float* a = g + (idx >> 5) * H + (idx & 31) * 8;                  \
      ld[j2][0] = *(const float4*)a;                                         \
      ld[j2][1] = *(const float4*)(a + 4);                                   \
    }                                                                        \
  }

  // ---- convert: ld regs f32 -> afrag[buf] bf16, fragment-linear layout ----
  // p = (ll*4 + hh + ss) & 63: write is bank-uniform (residues of (hh+ss)%8
  // are exactly 8 lanes each), read (GEMM1) is 64-distinct-p conflict-free.
#define CVT(buf)                                                             \
  {                                                                          \
    unsigned short* dst = afrag + (buf) * (BMT * H);                         \
    _Pragma("unroll") for (int j2 = 0; j2 < 4; ++j2) {                       \
      const int idx = tid + j2 * THREADS;                                    \
      const int row = idx >> 5, k8 = idx & 31;                               \
      const int ff = row >> 4, ss = k8 >> 2, hh = k8 & 3, ll = row & 15;     \
      const int p = (ll * 4 + hh + ss) & 63;                                 \
      *(bf16x8*)&dst[(ff * 8 + ss) * 512 + p * 8] = pack8(ld[j2][0], ld[j2][1]); \
    }                                                                        \
  }

  // ---- prologue: stage tile 0, put tile 1 in flight ----
  ISSUE(0);
  __builtin_amdgcn_sched_barrier(0);
  CVT(0);
  BAR();
  ISSUE(1);

  float psum[2] = {0.f, 0.f};
  float dsum = 0.f;
  int cur = 0;

  for (int t = 0; t < TPB; ++t) {
    const unsigned short* A = afrag + cur * (BMT * H);

    // ---- GEMM1: 4 f-frags x 2 coltiles, k=256, reads afrag[cur] ----
    f32x4 acc[4][2];
    #pragma unroll
    for (int f = 0; f < 4; ++f) { acc[f][0] = (f32x4)0.f; acc[f][1] = (f32x4)0.f; }
    #pragma unroll
    for (int s = 0; s < 8; ++s) {
      const int p = (l15 * 4 + hi + s) & 63;
      bf16x8 af[4];
      #pragma unroll
      for (int f = 0; f < 4; ++f)
        af[f] = *(const bf16x8*)&A[(f * 8 + s) * 512 + p * 8];
      #pragma unroll
      for (int f = 0; f < 4; ++f) {
        acc[f][0] = __builtin_amdgcn_mfma_f32_16x16x32_bf16(af[f], b1r[0][s], acc[f][0], 0, 0, 0);
        acc[f][1] = __builtin_amdgcn_mfma_f32_16x16x32_bf16(af[f], b1r[1][s], acc[f][1], 0, 0, 0);
      }
    }

    // ---- h = leaky(acc + b1) -> hbuf, writer-contiguous layout ----
    // element (row,k): page s2=k>>5, hb=(k>>3)&3, j2=k&7, rl=row&15
    // p = (hb&1) | (rl>>2)<<1 | (hb>>1)<<3 | (rl&3)<<4
    // writer view: hb&1 = l15>>3, hb>>1 = cc, rl>>2 = hi, rl&3 = r
    // -> per-inst lane offset = hi*32 + l15*2 : 128 contiguous bytes.
    #pragma unroll
    for (int cc = 0; cc < 2; ++cc) {
      const int col = (2 * w + cc) * 16 + l15;        // GEMM1 output col
      const int s2 = col >> 5;                        // = w
      const int e8 = (l15 >> 3) & 1;                  // hb&1
      const int j2 = col & 7;
      #pragma unroll
      for (int f = 0; f < 4; ++f) {
        #pragma unroll
        for (int r = 0; r < 4; ++r) {
          float hv = acc[f][cc][r] + bc1[cc];
          hv = fmaxf(hv, 0.02f * hv);                 // leaky relu
          const int p2 = e8 | (hi << 1) | (cc << 3) | (r << 4);
          hbuf[(f * 8 + s2) * 512 + p2 * 8 + j2] = f2bf(hv);
        }
      }
    }
    BAR();  // BAR1: h visible to all waves

    // ---- GEMM2: ae = h @ W2, reads hbuf (reader p: 64 distinct rows) ----
    const int ph = (hi & 1) | ((l15 >> 2) << 1) | ((hi >> 1) << 3) | ((l15 & 3) << 4);
    #pragma unroll
    for (int f = 0; f < 4; ++f) { acc[f][0] = (f32x4)0.f; acc[f][1] = (f32x4)0.f; }
    #pragma unroll
    for (int s = 0; s < 8; ++s) {
      bf16x8 af[4];
      #pragma unroll
      for (int f = 0; f < 4; ++f)
        af[f] = *(const bf16x8*)&hbuf[(f * 8 + s) * 512 + ph * 8];
      #pragma unroll
      for (int f = 0; f < 4; ++f) {
        acc[f][0] = __builtin_amdgcn_mfma_f32_16x16x32_bf16(af[f], b2r[0][s], acc[f][0], 0, 0, 0);
      }
      if (nct2 == 2) {
        #pragma unroll
        for (int f = 0; f < 4; ++f) {
          acc[f][1] = __builtin_amdgcn_mfma_f32_16x16x32_bf16(af[f], b2r[1][s], acc[f][1], 0, 0, 0);
        }
      }
    }

    // ---- e = exp(logit): col 0 lives in wave 0, lanes l15==0 ----
    if (w == 0 && l15 == 0) {
      #pragma unroll
      for (int f = 0; f < 4; ++f) {
        #pragma unroll
        for (int r = 0; r < 4; ++r) {
          e_lds[f * 16 + hi * 4 + r] = __expf(acc[f][0][r] + b2c0);
        }
      }
    }

    // ---- convert next tile into afrag[cur^1] (own sched region) ----
    if (t + 1 < TPB) {
      __builtin_amdgcn_sched_barrier(0);
      CVT(cur ^ 1);
      __builtin_amdgcn_sched_barrier(0);
    }
    BAR();  // BAR2: e_lds + converted afrag visible; all hbuf reads done

    // ---- accumulate softmax-weighted partials in registers ----
    #pragma unroll
    for (int f = 0; f < 4; ++f) {
      const f32x4 ev = *(const f32x4*)&e_lds[f * 16 + hi * 4];
      #pragma unroll
      for (int r = 0; r < 4; ++r) {
        psum[0] += ev[r] * (acc[f][0][r] + bj2[0]);
        if (nct2 == 2) psum[1] += ev[r] * (acc[f][1][r] + bj2[1]);
      }
    }
    if (w == 1) dsum += e_lds[l];

    // ---- prefetch tile t+2 (ld regs freed by CVT above) ----
    if (t + 2 < TPB) ISSUE(t + 2);

    cur ^= 1;
  }

  // ---- store per-block partials (no atomics) ----
  #pragma unroll
  for (int cc = 0; cc < 2; ++cc) {
    psum[cc] += __shfl_xor(psum[cc], 16);
    psum[cc] += __shfl_xor(psum[cc], 32);
  }
  if (hi == 0) {
    for (int cc = 0; cc < nct2; ++cc) {
      int j = jcol[cc];
      if (j >= 1 && j < OUTD) part[blk * PCOLS + (j - 1)] = psum[cc];
    }
  }
  if (w == 1) {
    #pragma unroll
    for (int m = 1; m < 64; m <<= 1) dsum += __shfl_xor(dsum, m);
    if (l == 0) part[blk * PCOLS + 217] = dsum;
  }
#undef ISSUE
#undef CVT
}

__global__ __launch_bounds__(256) void finalize_kernel(
    const float* __restrict__ part, float* __restrict__ out) {
  int b = blockIdx.x;
  int t = threadIdx.x;
  if (t < 217) {
    float s = 0.f, d = 0.f;
    #pragma unroll
    for (int i = 0; i < NBLK / NBATCH; ++i) {   // 4 blocks per batch
      const float* p = part + (size_t)(b * (NBLK / NBATCH) + i) * PCOLS;
      s += p[t];
      d += p[217];
    }
    float v = s / d;
    if (t < 216) out[b * 216 + t] = v;        // xr: (64, 72, 3) flat
    else out[NBATCH * 216 + b] = v;           // xo: (64,)
  }
}

extern "C" void kernel_launch(void* const* d_in, const int* in_sizes, int n_in,
                              void* d_out, int out_size, void* d_ws, size_t ws_size,
                              hipStream_t stream) {
  (void)in_sizes; (void)n_in; (void)out_size; (void)ws_size;
  const float* pe = (const float*)d_in[0];
  const float* W1 = (const float*)d_in[1];
  const float* b1 = (const float*)d_in[2];
  const float* W2 = (const float*)d_in[3];
  const float* b2 = (const float*)d_in[4];

  unsigned short* w1t = (unsigned short*)d_ws;          // 131072 B
  unsigned short* w2t = w1t + H * H;                    // 114688 B
  float* part = (float*)((char*)d_ws + (H * H + OUTP * H) * 2);  // 256*218*4 B

  prep_kernel<<<H + OUTP, 256, 0, stream>>>(W1, W2, w1t, w2t);
  fused_kernel<<<NBLK, THREADS, 0, stream>>>(pe, b1, b2, w1t, w2t, part);
  finalize_kernel<<<NBATCH, 256, 0, stream>>>(part, (float*)d_out);
}